// Round 14
// baseline (619.022 us; speedup 1.0000x reference)
//
#include <hip/hip_runtime.h>
#include <hip/hip_bf16.h>

typedef __bf16 bf16_t;
typedef __bf16 bf16x8 __attribute__((ext_vector_type(8)));
typedef __bf16 bf16x4 __attribute__((ext_vector_type(4)));
typedef float f32x4 __attribute__((ext_vector_type(4)));
typedef int i32x2 __attribute__((ext_vector_type(2)));
typedef unsigned char u8;

#define DI __device__ __forceinline__

DI f32x4 mfma16(bf16x8 a, bf16x8 b, f32x4 c) {
  return __builtin_amdgcn_mfma_f32_16x16x32_bf16(a, b, c, 0, 0, 0);
}
DI f32x4 mfma8(i32x2 a, i32x2 b, f32x4 c) {
  return __builtin_amdgcn_mfma_f32_16x16x32_fp8_fp8(
      __builtin_bit_cast(long, a), __builtin_bit_cast(long, b), c, 0, 0, 0);
}
DI void gload16(const void* g, void* l) {
  __builtin_amdgcn_global_load_lds(
      (const __attribute__((address_space(1))) unsigned int*)g,
      (__attribute__((address_space(3))) unsigned int*)l, 16, 0, 0);
}
DI u8 f2fp8(float x) {
  return (u8)(__builtin_amdgcn_cvt_pk_fp8_f32(x, x, 0, false) & 0xff);
}

__constant__ int GEO_c[15] = {1,2,3,4,5,6,8,10,22,23,29,31,32,33,43};
__constant__ int POS_c[11] = {9,16,17,20,27,30,36,42,48,49,50};
__constant__ int SEM_c[24] = {7,11,12,13,14,15,18,19,21,24,25,26,28,34,35,37,38,39,40,41,44,45,46,47};

// ---------- prep: transpose f32 Wpc [1024][4096] -> bf16 WpcT [4096][1024] ----------
__global__ void k_transpose(const float* __restrict__ src, bf16_t* __restrict__ dst,
                            int K, int N) {
  __shared__ float s[64][65];
  int n0 = blockIdx.x * 64, k0 = blockIdx.y * 64;
  int t = threadIdx.x;
#pragma unroll
  for (int i = 0; i < 4; ++i) {
    int idx = t + i * 256; int kr = idx >> 4, seg = idx & 15;
    float4 v = *(const float4*)(src + (size_t)(k0 + kr) * N + n0 + seg * 4);
    s[kr][seg * 4 + 0] = v.x; s[kr][seg * 4 + 1] = v.y;
    s[kr][seg * 4 + 2] = v.z; s[kr][seg * 4 + 3] = v.w;
  }
  __syncthreads();
#pragma unroll
  for (int i = 0; i < 4; ++i) {
    int idx = t + i * 256; int nr = idx >> 4, seg = idx & 15;
    bf16x4 h;
    h[0] = (bf16_t)s[seg * 4 + 0][nr]; h[1] = (bf16_t)s[seg * 4 + 1][nr];
    h[2] = (bf16_t)s[seg * 4 + 2][nr]; h[3] = (bf16_t)s[seg * 4 + 3][nr];
    *(bf16x4*)(dst + (size_t)(n0 + nr) * K + k0 + seg * 4) = h;
  }
}

// ---------- prep: pack Wc* (fp8) / Wv* (bf16) into [64][4096], bcv ----------
DI void cat_map(int j, int& which, int& sub, int& nc) {
  if (j < 15)      { which = 0; sub = j;      nc = 15; }
  else if (j < 26) { which = 1; sub = j - 15; nc = 11; }
  else if (j < 50) { which = 2; sub = j - 26; nc = 24; }
  else if (j < 54) { which = 3; sub = j - 50; nc = 4;  }
  else             { which = 4; sub = 0;      nc = 1;  }
}

__global__ void k_pack_cat(const float* __restrict__ Wc1, const float* __restrict__ Wc2,
                           const float* __restrict__ Wc3, const float* __restrict__ Wcs,
                           const float* __restrict__ Wv1, const float* __restrict__ Wv2,
                           const float* __restrict__ Wv3, const float* __restrict__ Wvs,
                           const float* __restrict__ bc1, const float* __restrict__ bc2,
                           const float* __restrict__ bc3, const float* __restrict__ bcs,
                           const float* __restrict__ bv1, const float* __restrict__ bv2,
                           const float* __restrict__ bv3, const float* __restrict__ bvs,
                           u8* __restrict__ WcF8, bf16_t* __restrict__ WvcatT,
                           float* __restrict__ bcv) {
  int j = blockIdx.x, t = threadIdx.x;
  int which, sub, nc; cat_map(j, which, sub, nc);
  const float* Wc = which == 0 ? Wc1 : which == 1 ? Wc2 : which == 2 ? Wc3 : Wcs;
  const float* Wv = which == 0 ? Wv1 : which == 1 ? Wv2 : which == 2 ? Wv3 : Wvs;
  for (int i = 0; i < 16; ++i) {
    int k = t + i * 256;
    float vc = 0.f, vv = 0.f;
    if (which < 4) { vc = Wc[(size_t)k * nc + sub]; vv = Wv[(size_t)k * nc + sub]; }
    WcF8[(size_t)j * 4096 + k] = f2fp8(vc);
    WvcatT[(size_t)j * 4096 + k] = (bf16_t)vv;
  }
  if (t == 0) {
    float b = 0.f;
    if (which < 4) {
      const float* bc = which == 0 ? bc1 : which == 1 ? bc2 : which == 2 ? bc3 : bcs;
      const float* bv = which == 0 ? bv1 : which == 1 ? bv2 : which == 2 ? bv3 : bvs;
      b = bc[sub] + bv[sub];
    }
    bcv[j] = b;
  }
}

// ---------- prep: ec f32 -> ecf8 ----------
__global__ __launch_bounds__(256) void k_ec8(const float* __restrict__ ec,
                                             u8* __restrict__ ecf8) {
  size_t i = ((size_t)blockIdx.x * 256 + threadIdx.x) * 8;
  float4 a = *(const float4*)(ec + i), b = *(const float4*)(ec + i + 4);
  int w0 = __builtin_amdgcn_cvt_pk_fp8_f32(a.x, a.y, 0, false);
  w0 = __builtin_amdgcn_cvt_pk_fp8_f32(a.z, a.w, w0, true);
  int w1 = __builtin_amdgcn_cvt_pk_fp8_f32(b.x, b.y, 0, false);
  w1 = __builtin_amdgcn_cvt_pk_fp8_f32(b.z, b.w, w1, true);
  i32x2 p; p[0] = w0; p[1] = w1;
  *(i32x2*)(ecf8 + i) = p;
}

// ---------- prep: W1/W2 fp8 (x64 scale) ----------
__global__ __launch_bounds__(256) void k_w12(const bf16_t* __restrict__ WpcT,
                                             const float* __restrict__ Wpe,
                                             u8* __restrict__ W1F8,
                                             u8* __restrict__ W2F8) {
  __shared__ bf16_t sA[128 * 64];
  __shared__ bf16_t sB[128 * 64];
  const int t = threadIdx.x, w = t >> 6, l = t & 63;
  const int lrow = l & 15, lkB = (l >> 4) << 4;
  const int k0 = blockIdx.x * 128, n0 = blockIdx.y * 128;
  const int joff = blockIdx.z * 512;
  u8* dst = blockIdx.z ? W2F8 : W1F8;

  f32x4 acc[2][8];
#pragma unroll
  for (int rf = 0; rf < 2; ++rf)
#pragma unroll
    for (int cf = 0; cf < 8; ++cf) { f32x4 z = {0.f, 0.f, 0.f, 0.f}; acc[rf][cf] = z; }

  for (int jj = 0; jj < 512; jj += 64) {
    __syncthreads();
#pragma unroll
    for (int i = 0; i < 4; ++i) {
      int row = (t >> 3) + (i << 5), seg = t & 7;
      bf16x8 v = *(const bf16x8*)(WpcT + (size_t)(n0 + row) * 1024 + joff + jj + seg * 8);
      *(bf16x8*)((char*)sA + (row << 7) + ((seg << 4) ^ ((row & 7) << 4))) = v;
    }
#pragma unroll
    for (int i = 0; i < 8; ++i) {
      int idx = t + i * 256; int row = idx >> 4, seg = idx & 15;
      float4 v = *(const float4*)(Wpe + (size_t)(k0 + row) * 1024 + joff + jj + seg * 4);
      bf16x4 h; h[0] = (bf16_t)v.x; h[1] = (bf16_t)v.y; h[2] = (bf16_t)v.z; h[3] = (bf16_t)v.w;
      *(bf16x4*)((char*)sB + (row << 7) + ((seg << 3) ^ ((row & 7) << 4))) = h;
    }
    __syncthreads();
#pragma unroll
    for (int ks = 0; ks < 2; ++ks) {
      bf16x8 af[2], bfr[8];
#pragma unroll
      for (int rf = 0; rf < 2; ++rf) {
        int row = w * 32 + rf * 16 + lrow;
        af[rf] = *(const bf16x8*)((const char*)sA + (row << 7) + (((ks << 6) | lkB) ^ ((row & 7) << 4)));
      }
#pragma unroll
      for (int cf = 0; cf < 8; ++cf) {
        int col = cf * 16 + lrow;
        bfr[cf] = *(const bf16x8*)((const char*)sB + (col << 7) + (((ks << 6) | lkB) ^ ((col & 7) << 4)));
      }
#pragma unroll
      for (int rf = 0; rf < 2; ++rf)
#pragma unroll
        for (int cf = 0; cf < 8; ++cf)
          acc[rf][cf] = mfma16(af[rf], bfr[cf], acc[rf][cf]);
    }
  }
#pragma unroll
  for (int cf = 0; cf < 8; ++cf)
#pragma unroll
    for (int rf = 0; rf < 2; ++rf)
#pragma unroll
      for (int r = 0; r < 4; ++r) {
        int nrow = n0 + w * 32 + rf * 16 + ((l >> 4) << 2) + r;
        dst[(size_t)nrow * 512 + k0 + cf * 16 + lrow] = f2fp8(acc[rf][cf][r] * 64.f);
      }
}

// ---------- prep: b12 (x64 scaled) ----------
__global__ __launch_bounds__(256) void k_bias(const bf16_t* __restrict__ WpcT,
                                              const float* __restrict__ bpe,
                                              const float* __restrict__ bpc,
                                              float* __restrict__ b12) {
  int w = threadIdx.x >> 6, l = threadIdx.x & 63;
  int n = blockIdx.x * 4 + w;
  const bf16_t* r = WpcT + (size_t)n * 1024;
  bf16x8 v1 = *(const bf16x8*)(r + l * 8);
  bf16x8 v2 = *(const bf16x8*)(r + 512 + l * 8);
  float s1 = 0.f, s2 = 0.f;
#pragma unroll
  for (int e = 0; e < 8; ++e) {
    s1 += (float)v1[e] * bpe[l * 8 + e];
    s2 += (float)v2[e] * bpe[512 + l * 8 + e];
  }
#pragma unroll
  for (int off = 32; off; off >>= 1) {
    s1 += __shfl_down(s1, off);
    s2 += __shfl_down(s2, off);
  }
  if (l == 0) { b12[n] = 64.f * (s1 + bpc[n]); b12[4096 + n] = 64.f * s2; }
}

// ---------- k_ht6: HU/TU(fp8, x64) = ecf8 @ W{1,2}F8 + b12, fp8 MFMA, 2 blocks/CU ----------
__global__ __launch_bounds__(512, 4) void k_ht6(const u8* __restrict__ ecf8,
                                                const u8* __restrict__ W1F8,
                                                const u8* __restrict__ W2F8,
                                                const float* __restrict__ b12,
                                                u8* __restrict__ HU,
                                                u8* __restrict__ TU) {
  __shared__ u8 sA[2][16384];   // [256 rows][64 k] fp8, swizzled
  __shared__ u8 sB[2][16384];
  const int t = threadIdx.x, wid = t >> 6, l = t & 63;
  const int lrow = l & 15, lseg = l >> 4;
  const int wr = wid >> 2, wc = wid & 3;
  const int n0 = blockIdx.x * 256, m0 = blockIdx.y * 256, z = blockIdx.z;
  const u8* Bw = z ? W2F8 : W1F8;
  const float* bias = b12 + z * 4096;
  u8* dst = z ? TU : HU;

  const u8* gA[2]; const u8* gB[2]; int ldsP[2];
#pragma unroll
  for (int i = 0; i < 2; ++i) {
    int slot = t + i * 512, row = slot >> 2, seg = slot & 3;
    int u = seg ^ (row & 3);
    gA[i] = ecf8 + (size_t)(m0 + row) * 512 + u * 16;
    gB[i] = Bw + (size_t)(n0 + row) * 512 + u * 16;
    ldsP[i] = slot * 16;
  }

  int aOff[2][8], bOff[2][4];
#pragma unroll
  for (int ks = 0; ks < 2; ++ks) {
#pragma unroll
    for (int rf = 0; rf < 8; ++rf) {
      int row = wr * 128 + rf * 16 + lrow;
      aOff[ks][rf] = row * 64 + (((ks * 2 + (lseg >> 1)) ^ (row & 3)) * 16) + (lseg & 1) * 8;
    }
#pragma unroll
    for (int cf = 0; cf < 4; ++cf) {
      int col = wc * 64 + cf * 16 + lrow;
      bOff[ks][cf] = col * 64 + (((ks * 2 + (lseg >> 1)) ^ (col & 3)) * 16) + (lseg & 1) * 8;
    }
  }

  f32x4 acc[8][4];
#pragma unroll
  for (int rf = 0; rf < 8; ++rf)
#pragma unroll
    for (int cf = 0; cf < 4; ++cf) { f32x4 zz = {0.f, 0.f, 0.f, 0.f}; acc[rf][cf] = zz; }

#pragma unroll
  for (int i = 0; i < 2; ++i) { gload16(gA[i], &sA[0][ldsP[i]]); gload16(gB[i], &sB[0][ldsP[i]]); }

#pragma unroll 1
  for (int tt = 0; tt < 8; ++tt) {
    const int cur = tt & 1;
    if (tt < 7) {
      const int kk = (tt + 1) * 64;
#pragma unroll
      for (int i = 0; i < 2; ++i) {
        gload16(gA[i] + kk, &sA[cur ^ 1][ldsP[i]]);
        gload16(gB[i] + kk, &sB[cur ^ 1][ldsP[i]]);
      }
      asm volatile("s_waitcnt vmcnt(4)" ::: "memory");
    } else {
      asm volatile("s_waitcnt vmcnt(0)" ::: "memory");
    }
    __syncthreads();
#pragma unroll
    for (int ks = 0; ks < 2; ++ks) {
      i32x2 af[8], bfr[4];
#pragma unroll
      for (int rf = 0; rf < 8; ++rf)
        af[rf] = *(const i32x2*)(&sA[cur][aOff[ks][rf]]);
#pragma unroll
      for (int cf = 0; cf < 4; ++cf)
        bfr[cf] = *(const i32x2*)(&sB[cur][bOff[ks][cf]]);
#pragma unroll
      for (int rf = 0; rf < 8; ++rf)
#pragma unroll
        for (int cf = 0; cf < 4; ++cf)
          acc[rf][cf] = mfma8(af[rf], bfr[cf], acc[rf][cf]);
    }
    __syncthreads();
  }

#pragma unroll
  for (int cf = 0; cf < 4; ++cf) {
    float bb = bias[n0 + wc * 64 + cf * 16 + lrow];
#pragma unroll
    for (int rf = 0; rf < 8; ++rf)
#pragma unroll
      for (int r = 0; r < 4; ++r) {
        int row = m0 + wr * 128 + rf * 16 + lseg * 4 + r;
        dst[(size_t)row * 4096 + n0 + wc * 64 + cf * 16 + lrow] = f2fp8(acc[rf][cf][r] + bb);
      }
  }
}

// ---------- k_out8: 128 pairs/block; fp8 everywhere except vis/Wv; 2 blocks/CU ----------
__global__ __launch_bounds__(512, 4) void k_out8(
    const u8* __restrict__ HU, const u8* __restrict__ TU,
    const u8* __restrict__ WcF8, const bf16_t* __restrict__ WvcatT,
    const float* __restrict__ bcv,
    const int* __restrict__ pair_idx, const int* __restrict__ pair_pred,
    const float* __restrict__ vis, const float* __restrict__ freq,
    float* __restrict__ out) {
  // buf layout (28 KB): HU [0,8K) | TU [8K,16K) | Wc [16K,20K) | Wv [20K,28K)
  __shared__ char smem[57344];
  __shared__ int sR0[128], sR1[128];

  const int t = threadIdx.x, wid = t >> 6, l = t & 63;
  const int lrow = l & 15, lseg = l >> 4;
  const int p0 = blockIdx.x * 128;

  if (t < 128) { sR0[t] = pair_idx[(p0 + t) * 2]; sR1[t] = pair_idx[(p0 + t) * 2 + 1]; }
  __syncthreads();

  const u8* srcH; const u8* srcT; int ldsG;
  {
    int row = t >> 2, seg = t & 3;
    int u = seg ^ (row & 3);
    srcH = HU + (size_t)sR0[row] * 4096 + u * 16;
    srcT = TU + (size_t)sR1[row] * 4096 + u * 16;
    ldsG = t * 16;
  }
  const u8* srcWc = nullptr; int ldsWc = 0;
  if (t >= 256) {
    int s = t - 256, col = s >> 2, seg = s & 3;
    int u = seg ^ (col & 3);
    srcWc = WcF8 + (size_t)col * 4096 + u * 16;
    ldsWc = 16384 + s * 16;
  }
  const bf16_t* srcWv; int ldsWv;
  {
    int col = t >> 3, seg = t & 7;
    int u = seg ^ (col & 7);
    srcWv = WvcatT + (size_t)col * 4096 + u * 8;
    ldsWv = 20480 + t * 16;
  }

  const float* vb = vis + (size_t)(p0 + wid * 16 + lrow) * 4096 + lseg * 8;

  const int ra = wid * 16 + lrow;
  int pOff[2];
#pragma unroll
  for (int ks = 0; ks < 2; ++ks) {
    int unit = ks * 2 + (lseg >> 1);
    pOff[ks] = ra * 64 + ((unit ^ (ra & 3)) * 16) + (lseg & 1) * 8;
  }

  f32x4 acc[4];
#pragma unroll
  for (int cf = 0; cf < 4; ++cf) { f32x4 z = {0.f, 0.f, 0.f, 0.f}; acc[cf] = z; }

  auto stage = [&](int tt) {
    const int ke = tt * 64;
    char* b = smem + (tt & 1) * 28672;
    gload16(srcH + ke, b + ldsG);
    gload16(srcT + ke, b + 8192 + ldsG);
    gload16(srcWv + (size_t)ke, b + ldsWv);
    if (t >= 256) gload16(srcWc + ke, b + ldsWc);
  };

  int wcFrag[2][4], wvFrag[2][4];
#pragma unroll
  for (int ks = 0; ks < 2; ++ks)
#pragma unroll
    for (int cf = 0; cf < 4; ++cf) {
      int col = cf * 16 + lrow;
      int unit = (ks * 2 + (lseg >> 1)) ^ (col & 3);
      wcFrag[ks][cf] = 16384 + col * 64 + unit * 16 + (lseg & 1) * 8;
      wvFrag[ks][cf] = 20480 + col * 128 + (((ks * 4 + lseg) ^ (col & 7)) * 16);
    }

  stage(0);

#pragma unroll 1
  for (int tt = 0; tt < 64; ++tt) {
    const char* b = smem + (tt & 1) * 28672;
    const int kb = tt * 64;
    f32x4 vv[4];
#pragma unroll
    for (int ks = 0; ks < 2; ++ks) {
      vv[ks * 2 + 0] = *(const f32x4*)(vb + kb + ks * 32);
      vv[ks * 2 + 1] = *(const f32x4*)(vb + kb + ks * 32 + 4);
    }
    __builtin_amdgcn_sched_barrier(0);
    if (tt < 63) {
      stage(tt + 1);
      __builtin_amdgcn_sched_barrier(0);
      asm volatile("s_waitcnt vmcnt(7)" ::: "memory");
    } else {
      asm volatile("s_waitcnt vmcnt(4)" ::: "memory");
    }
    __syncthreads();
#pragma unroll
    for (int ks = 0; ks < 2; ++ks) {
      i32x2 hv = *(const i32x2*)(b + pOff[ks]);
      i32x2 tv = *(const i32x2*)(b + 8192 + pOff[ks]);
      int h0 = hv[0], h1 = hv[1], t0 = tv[0], t1 = tv[1];
      const float us = 0.015625f;   // 1/64
      float f0 = fmaxf(__builtin_amdgcn_cvt_f32_fp8(h0, 0) + __builtin_amdgcn_cvt_f32_fp8(t0, 0), 0.f) * us;
      float f1 = fmaxf(__builtin_amdgcn_cvt_f32_fp8(h0, 1) + __builtin_amdgcn_cvt_f32_fp8(t0, 1), 0.f) * us;
      float f2 = fmaxf(__builtin_amdgcn_cvt_f32_fp8(h0, 2) + __builtin_amdgcn_cvt_f32_fp8(t0, 2), 0.f) * us;
      float f3 = fmaxf(__builtin_amdgcn_cvt_f32_fp8(h0, 3) + __builtin_amdgcn_cvt_f32_fp8(t0, 3), 0.f) * us;
      float f4 = fmaxf(__builtin_amdgcn_cvt_f32_fp8(h1, 0) + __builtin_amdgcn_cvt_f32_fp8(t1, 0), 0.f) * us;
      float f5 = fmaxf(__builtin_amdgcn_cvt_f32_fp8(h1, 1) + __builtin_amdgcn_cvt_f32_fp8(t1, 1), 0.f) * us;
      float f6 = fmaxf(__builtin_amdgcn_cvt_f32_fp8(h1, 2) + __builtin_amdgcn_cvt_f32_fp8(t1, 2), 0.f) * us;
      float f7 = fmaxf(__builtin_amdgcn_cvt_f32_fp8(h1, 3) + __builtin_amdgcn_cvt_f32_fp8(t1, 3), 0.f) * us;
      i32x2 pa;
      {
        int w0 = __builtin_amdgcn_cvt_pk_fp8_f32(f0, f1, 0, false);
        w0 = __builtin_amdgcn_cvt_pk_fp8_f32(f2, f3, w0, true);
        int w1 = __builtin_amdgcn_cvt_pk_fp8_f32(f4, f5, 0, false);
        w1 = __builtin_amdgcn_cvt_pk_fp8_f32(f6, f7, w1, true);
        pa[0] = w0; pa[1] = w1;
      }
#pragma unroll
      for (int cf = 0; cf < 4; ++cf) {
        i32x2 bw = *(const i32x2*)(b + wcFrag[ks][cf]);
        acc[cf] = mfma8(pa, bw, acc[cf]);
      }
      f32x4 v0 = vv[ks * 2 + 0], v1 = vv[ks * 2 + 1];
      bf16x8 ag;
      ag[0] = (bf16_t)v0[0]; ag[1] = (bf16_t)v0[1]; ag[2] = (bf16_t)v0[2]; ag[3] = (bf16_t)v0[3];
      ag[4] = (bf16_t)v1[0]; ag[5] = (bf16_t)v1[1]; ag[6] = (bf16_t)v1[2]; ag[7] = (bf16_t)v1[3];
#pragma unroll
      for (int cf = 0; cf < 4; ++cf) {
        bf16x8 bw = *(const bf16x8*)(b + wvFrag[ks][cf]);
        acc[cf] = mfma16(ag, bw, acc[cf]);
      }
    }
    __syncthreads();
  }

  // epilogue
  float* sF = (float*)smem;
#pragma unroll
  for (int cf = 0; cf < 4; ++cf) {
    float bb = bcv[cf * 16 + lrow];
#pragma unroll
    for (int r = 0; r < 4; ++r) {
      int row = wid * 16 + lseg * 4 + r;
      sF[row * 64 + cf * 16 + lrow] = acc[cf][r] + bb;
    }
  }
  __syncthreads();
  if (t < 128) {
    int p = p0 + t;
    const float* f = freq + ((size_t)pair_pred[p * 2] * 151 + pair_pred[p * 2 + 1]) * 51;
    const float* rowv = sF + t * 64;
    float e1 = 0.f, e2 = 0.f, e3 = 0.f;
#pragma unroll
    for (int c = 0; c < 15; ++c) {
      float fb = f[GEO_c[c]]; e1 += expf(fb);
      out[(size_t)p * 15 + c] = rowv[c] + fb;
    }
#pragma unroll
    for (int c = 0; c < 11; ++c) {
      float fb = f[POS_c[c]]; e2 += expf(fb);
      out[491520 + (size_t)p * 11 + c] = rowv[15 + c] + fb;
    }
#pragma unroll
    for (int c = 0; c < 24; ++c) {
      float fb = f[SEM_c[c]]; e3 += expf(fb);
      out[851968 + (size_t)p * 24 + c] = rowv[26 + c] + fb;
    }
    out[1638400 + (size_t)p * 4 + 0] = rowv[50] + f[0];
    out[1638400 + (size_t)p * 4 + 1] = rowv[51] + logf(e1);
    out[1638400 + (size_t)p * 4 + 2] = rowv[52] + logf(e2);
    out[1638400 + (size_t)p * 4 + 3] = rowv[53] + logf(e3);
  }
}

extern "C" void kernel_launch(void* const* d_in, const int* in_sizes, int n_in,
                              void* d_out, int out_size, void* d_ws, size_t ws_size,
                              hipStream_t stream) {
  const float* edge_ctx  = (const float*)d_in[0];
  const int*   pair_idx  = (const int*)d_in[1];
  const float* vis_rep   = (const float*)d_in[2];
  const int*   pair_pred = (const int*)d_in[3];
  const float* Wpe = (const float*)d_in[4];
  const float* bpe = (const float*)d_in[5];
  const float* Wpc = (const float*)d_in[6];
  const float* bpc = (const float*)d_in[7];
  const float* Wc1 = (const float*)d_in[8];  const float* bc1 = (const float*)d_in[9];
  const float* Wc2 = (const float*)d_in[10]; const float* bc2 = (const float*)d_in[11];
  const float* Wc3 = (const float*)d_in[12]; const float* bc3 = (const float*)d_in[13];
  const float* Wcs = (const float*)d_in[14]; const float* bcs = (const float*)d_in[15];
  const float* Wv1 = (const float*)d_in[16]; const float* bv1 = (const float*)d_in[17];
  const float* Wv2 = (const float*)d_in[18]; const float* bv2 = (const float*)d_in[19];
  const float* Wv3 = (const float*)d_in[20]; const float* bv3 = (const float*)d_in[21];
  const float* Wvs = (const float*)d_in[22]; const float* bvs = (const float*)d_in[23];
  const float* freq = (const float*)d_in[24];
  float* out = (float*)d_out;

  char* ws = (char*)d_ws;
  bf16_t* WpcT   = (bf16_t*)(ws + 0);           //  8388608
  u8*     W1F8   = (u8*)(ws + 8388608);         //  2097152
  u8*     W2F8   = (u8*)(ws + 10485760);        //  2097152
  u8*     ecf8   = (u8*)(ws + 12582912);        //  4194304
  u8*     WcF8   = (u8*)(ws + 16777216);        //   262144
  bf16_t* WvcatT = (bf16_t*)(ws + 17039360);    //   524288
  float*  bcv    = (float*)(ws + 17563648);     //     4096
  float*  b12    = (float*)(ws + 17567744);     //    32768
  u8*     HU     = (u8*)(ws + 17600512);        // 33554432
  u8*     TU     = (u8*)(ws + 51154944);        // 33554432  -> end 84709376

  k_transpose<<<dim3(64, 16), 256, 0, stream>>>(Wpc, WpcT, 1024, 4096);
  k_pack_cat<<<64, 256, 0, stream>>>(Wc1, Wc2, Wc3, Wcs, Wv1, Wv2, Wv3, Wvs,
                                     bc1, bc2, bc3, bcs, bv1, bv2, bv3, bvs,
                                     WcF8, WvcatT, bcv);
  k_ec8<<<2048, 256, 0, stream>>>(edge_ctx, ecf8);
  k_w12<<<dim3(4, 32, 2), 256, 0, stream>>>(WpcT, Wpe, W1F8, W2F8);
  k_bias<<<1024, 256, 0, stream>>>(WpcT, bpe, bpc, b12);
  k_ht6<<<dim3(16, 32, 2), 512, 0, stream>>>(ecf8, W1F8, W2F8, b12, HU, TU);
  k_out8<<<256, 512, 0, stream>>>(HU, TU, WcF8, WvcatT, bcv,
                                  pair_idx, pair_pred, vis_rep, freq, out);
}

// Round 15
// 330.481 us; speedup vs baseline: 1.8731x; 1.8731x over previous
//
#include <hip/hip_runtime.h>
#include <hip/hip_bf16.h>

typedef __bf16 bf16_t;
typedef __bf16 bf16x8 __attribute__((ext_vector_type(8)));
typedef __bf16 bf16x4 __attribute__((ext_vector_type(4)));
typedef float f32x4 __attribute__((ext_vector_type(4)));
typedef int i32x2 __attribute__((ext_vector_type(2)));
typedef unsigned char u8;

#define DI __device__ __forceinline__

DI f32x4 mfma16(bf16x8 a, bf16x8 b, f32x4 c) {
  return __builtin_amdgcn_mfma_f32_16x16x32_bf16(a, b, c, 0, 0, 0);
}
DI f32x4 mfma8(i32x2 a, i32x2 b, f32x4 c) {
  return __builtin_amdgcn_mfma_f32_16x16x32_fp8_fp8(
      __builtin_bit_cast(long, a), __builtin_bit_cast(long, b), c, 0, 0, 0);
}
DI void gload16(const void* g, void* l) {
  __builtin_amdgcn_global_load_lds(
      (const __attribute__((address_space(1))) unsigned int*)g,
      (__attribute__((address_space(3))) unsigned int*)l, 16, 0, 0);
}
DI u8 f2fp8(float x) {
  return (u8)(__builtin_amdgcn_cvt_pk_fp8_f32(x, x, 0, false) & 0xff);
}

__constant__ int GEO_c[15] = {1,2,3,4,5,6,8,10,22,23,29,31,32,33,43};
__constant__ int POS_c[11] = {9,16,17,20,27,30,36,42,48,49,50};
__constant__ int SEM_c[24] = {7,11,12,13,14,15,18,19,21,24,25,26,28,34,35,37,38,39,40,41,44,45,46,47};

// ---------- prep: transpose f32 Wpc [1024][4096] -> bf16 WpcT [4096][1024] ----------
__global__ void k_transpose(const float* __restrict__ src, bf16_t* __restrict__ dst,
                            int K, int N) {
  __shared__ float s[64][65];
  int n0 = blockIdx.x * 64, k0 = blockIdx.y * 64;
  int t = threadIdx.x;
#pragma unroll
  for (int i = 0; i < 4; ++i) {
    int idx = t + i * 256; int kr = idx >> 4, seg = idx & 15;
    float4 v = *(const float4*)(src + (size_t)(k0 + kr) * N + n0 + seg * 4);
    s[kr][seg * 4 + 0] = v.x; s[kr][seg * 4 + 1] = v.y;
    s[kr][seg * 4 + 2] = v.z; s[kr][seg * 4 + 3] = v.w;
  }
  __syncthreads();
#pragma unroll
  for (int i = 0; i < 4; ++i) {
    int idx = t + i * 256; int nr = idx >> 4, seg = idx & 15;
    bf16x4 h;
    h[0] = (bf16_t)s[seg * 4 + 0][nr]; h[1] = (bf16_t)s[seg * 4 + 1][nr];
    h[2] = (bf16_t)s[seg * 4 + 2][nr]; h[3] = (bf16_t)s[seg * 4 + 3][nr];
    *(bf16x4*)(dst + (size_t)(n0 + nr) * K + k0 + seg * 4) = h;
  }
}

// ---------- prep: pack Wc* (fp8) / Wv* (bf16) into [64][4096], bcv ----------
DI void cat_map(int j, int& which, int& sub, int& nc) {
  if (j < 15)      { which = 0; sub = j;      nc = 15; }
  else if (j < 26) { which = 1; sub = j - 15; nc = 11; }
  else if (j < 50) { which = 2; sub = j - 26; nc = 24; }
  else if (j < 54) { which = 3; sub = j - 50; nc = 4;  }
  else             { which = 4; sub = 0;      nc = 1;  }
}

__global__ void k_pack_cat(const float* __restrict__ Wc1, const float* __restrict__ Wc2,
                           const float* __restrict__ Wc3, const float* __restrict__ Wcs,
                           const float* __restrict__ Wv1, const float* __restrict__ Wv2,
                           const float* __restrict__ Wv3, const float* __restrict__ Wvs,
                           const float* __restrict__ bc1, const float* __restrict__ bc2,
                           const float* __restrict__ bc3, const float* __restrict__ bcs,
                           const float* __restrict__ bv1, const float* __restrict__ bv2,
                           const float* __restrict__ bv3, const float* __restrict__ bvs,
                           u8* __restrict__ WcF8, bf16_t* __restrict__ WvcatT,
                           float* __restrict__ bcv) {
  int j = blockIdx.x, t = threadIdx.x;
  int which, sub, nc; cat_map(j, which, sub, nc);
  const float* Wc = which == 0 ? Wc1 : which == 1 ? Wc2 : which == 2 ? Wc3 : Wcs;
  const float* Wv = which == 0 ? Wv1 : which == 1 ? Wv2 : which == 2 ? Wv3 : Wvs;
  for (int i = 0; i < 16; ++i) {
    int k = t + i * 256;
    float vc = 0.f, vv = 0.f;
    if (which < 4) { vc = Wc[(size_t)k * nc + sub]; vv = Wv[(size_t)k * nc + sub]; }
    WcF8[(size_t)j * 4096 + k] = f2fp8(vc);
    WvcatT[(size_t)j * 4096 + k] = (bf16_t)vv;
  }
  if (t == 0) {
    float b = 0.f;
    if (which < 4) {
      const float* bc = which == 0 ? bc1 : which == 1 ? bc2 : which == 2 ? bc3 : bcs;
      const float* bv = which == 0 ? bv1 : which == 1 ? bv2 : which == 2 ? bv3 : bvs;
      b = bc[sub] + bv[sub];
    }
    bcv[j] = b;
  }
}

// ---------- prep: ec f32 -> ecf8 ----------
__global__ __launch_bounds__(256) void k_ec8(const float* __restrict__ ec,
                                             u8* __restrict__ ecf8) {
  size_t i = ((size_t)blockIdx.x * 256 + threadIdx.x) * 8;
  float4 a = *(const float4*)(ec + i), b = *(const float4*)(ec + i + 4);
  int w0 = __builtin_amdgcn_cvt_pk_fp8_f32(a.x, a.y, 0, false);
  w0 = __builtin_amdgcn_cvt_pk_fp8_f32(a.z, a.w, w0, true);
  int w1 = __builtin_amdgcn_cvt_pk_fp8_f32(b.x, b.y, 0, false);
  w1 = __builtin_amdgcn_cvt_pk_fp8_f32(b.z, b.w, w1, true);
  i32x2 p; p[0] = w0; p[1] = w1;
  *(i32x2*)(ecf8 + i) = p;
}

// ---------- prep: W1/W2 fp8 (x64 scale) ----------
__global__ __launch_bounds__(256) void k_w12(const bf16_t* __restrict__ WpcT,
                                             const float* __restrict__ Wpe,
                                             u8* __restrict__ W1F8,
                                             u8* __restrict__ W2F8) {
  __shared__ bf16_t sA[128 * 64];
  __shared__ bf16_t sB[128 * 64];
  const int t = threadIdx.x, w = t >> 6, l = t & 63;
  const int lrow = l & 15, lkB = (l >> 4) << 4;
  const int k0 = blockIdx.x * 128, n0 = blockIdx.y * 128;
  const int joff = blockIdx.z * 512;
  u8* dst = blockIdx.z ? W2F8 : W1F8;

  f32x4 acc[2][8];
#pragma unroll
  for (int rf = 0; rf < 2; ++rf)
#pragma unroll
    for (int cf = 0; cf < 8; ++cf) { f32x4 z = {0.f, 0.f, 0.f, 0.f}; acc[rf][cf] = z; }

  for (int jj = 0; jj < 512; jj += 64) {
    __syncthreads();
#pragma unroll
    for (int i = 0; i < 4; ++i) {
      int row = (t >> 3) + (i << 5), seg = t & 7;
      bf16x8 v = *(const bf16x8*)(WpcT + (size_t)(n0 + row) * 1024 + joff + jj + seg * 8);
      *(bf16x8*)((char*)sA + (row << 7) + ((seg << 4) ^ ((row & 7) << 4))) = v;
    }
#pragma unroll
    for (int i = 0; i < 8; ++i) {
      int idx = t + i * 256; int row = idx >> 4, seg = idx & 15;
      float4 v = *(const float4*)(Wpe + (size_t)(k0 + row) * 1024 + joff + jj + seg * 4);
      bf16x4 h; h[0] = (bf16_t)v.x; h[1] = (bf16_t)v.y; h[2] = (bf16_t)v.z; h[3] = (bf16_t)v.w;
      *(bf16x4*)((char*)sB + (row << 7) + ((seg << 3) ^ ((row & 7) << 4))) = h;
    }
    __syncthreads();
#pragma unroll
    for (int ks = 0; ks < 2; ++ks) {
      bf16x8 af[2], bfr[8];
#pragma unroll
      for (int rf = 0; rf < 2; ++rf) {
        int row = w * 32 + rf * 16 + lrow;
        af[rf] = *(const bf16x8*)((const char*)sA + (row << 7) + (((ks << 6) | lkB) ^ ((row & 7) << 4)));
      }
#pragma unroll
      for (int cf = 0; cf < 8; ++cf) {
        int col = cf * 16 + lrow;
        bfr[cf] = *(const bf16x8*)((const char*)sB + (col << 7) + (((ks << 6) | lkB) ^ ((col & 7) << 4)));
      }
#pragma unroll
      for (int rf = 0; rf < 2; ++rf)
#pragma unroll
        for (int cf = 0; cf < 8; ++cf)
          acc[rf][cf] = mfma16(af[rf], bfr[cf], acc[rf][cf]);
    }
  }
#pragma unroll
  for (int cf = 0; cf < 8; ++cf)
#pragma unroll
    for (int rf = 0; rf < 2; ++rf)
#pragma unroll
      for (int r = 0; r < 4; ++r) {
        int nrow = n0 + w * 32 + rf * 16 + ((l >> 4) << 2) + r;
        dst[(size_t)nrow * 512 + k0 + cf * 16 + lrow] = f2fp8(acc[rf][cf][r] * 64.f);
      }
}

// ---------- prep: b12 (x64 scaled) ----------
__global__ __launch_bounds__(256) void k_bias(const bf16_t* __restrict__ WpcT,
                                              const float* __restrict__ bpe,
                                              const float* __restrict__ bpc,
                                              float* __restrict__ b12) {
  int w = threadIdx.x >> 6, l = threadIdx.x & 63;
  int n = blockIdx.x * 4 + w;
  const bf16_t* r = WpcT + (size_t)n * 1024;
  bf16x8 v1 = *(const bf16x8*)(r + l * 8);
  bf16x8 v2 = *(const bf16x8*)(r + 512 + l * 8);
  float s1 = 0.f, s2 = 0.f;
#pragma unroll
  for (int e = 0; e < 8; ++e) {
    s1 += (float)v1[e] * bpe[l * 8 + e];
    s2 += (float)v2[e] * bpe[512 + l * 8 + e];
  }
#pragma unroll
  for (int off = 32; off; off >>= 1) {
    s1 += __shfl_down(s1, off);
    s2 += __shfl_down(s2, off);
  }
  if (l == 0) { b12[n] = 64.f * (s1 + bpc[n]); b12[4096 + n] = 64.f * s2; }
}

// ---------- k_ht6: HU/TU(fp8, x64) = ecf8 @ W{1,2}F8 + b12, fp8 MFMA ----------
// swizzle f(row) = (row>>1)&3 -> 2-way (free) bank pattern on 64B fp8 rows
__global__ __launch_bounds__(512, 1) void k_ht6(const u8* __restrict__ ecf8,
                                                const u8* __restrict__ W1F8,
                                                const u8* __restrict__ W2F8,
                                                const float* __restrict__ b12,
                                                u8* __restrict__ HU,
                                                u8* __restrict__ TU) {
  __shared__ u8 sA[2][16384];
  __shared__ u8 sB[2][16384];
  const int t = threadIdx.x, wid = t >> 6, l = t & 63;
  const int lrow = l & 15, lseg = l >> 4;
  const int wr = wid >> 2, wc = wid & 3;
  const int n0 = blockIdx.x * 256, m0 = blockIdx.y * 256, z = blockIdx.z;
  const u8* Bw = z ? W2F8 : W1F8;
  const float* bias = b12 + z * 4096;
  u8* dst = z ? TU : HU;

  const u8* gA[2]; const u8* gB[2]; int ldsP[2];
#pragma unroll
  for (int i = 0; i < 2; ++i) {
    int slot = t + i * 512, row = slot >> 2, seg = slot & 3;
    int u = seg ^ ((row >> 1) & 3);
    gA[i] = ecf8 + (size_t)(m0 + row) * 512 + u * 16;
    gB[i] = Bw + (size_t)(n0 + row) * 512 + u * 16;
    ldsP[i] = slot * 16;
  }

  int aOff[2][8], bOff[2][4];
#pragma unroll
  for (int ks = 0; ks < 2; ++ks) {
#pragma unroll
    for (int rf = 0; rf < 8; ++rf) {
      int row = wr * 128 + rf * 16 + lrow;
      aOff[ks][rf] = row * 64 + (((ks * 2 + (lseg >> 1)) ^ ((row >> 1) & 3)) * 16) + (lseg & 1) * 8;
    }
#pragma unroll
    for (int cf = 0; cf < 4; ++cf) {
      int col = wc * 64 + cf * 16 + lrow;
      bOff[ks][cf] = col * 64 + (((ks * 2 + (lseg >> 1)) ^ ((col >> 1) & 3)) * 16) + (lseg & 1) * 8;
    }
  }

  f32x4 acc[8][4];
#pragma unroll
  for (int rf = 0; rf < 8; ++rf)
#pragma unroll
    for (int cf = 0; cf < 4; ++cf) { f32x4 zz = {0.f, 0.f, 0.f, 0.f}; acc[rf][cf] = zz; }

#pragma unroll
  for (int i = 0; i < 2; ++i) { gload16(gA[i], &sA[0][ldsP[i]]); gload16(gB[i], &sB[0][ldsP[i]]); }

#pragma unroll 1
  for (int tt = 0; tt < 8; ++tt) {
    const int cur = tt & 1;
    if (tt < 7) {
      const int kk = (tt + 1) * 64;
#pragma unroll
      for (int i = 0; i < 2; ++i) {
        gload16(gA[i] + kk, &sA[cur ^ 1][ldsP[i]]);
        gload16(gB[i] + kk, &sB[cur ^ 1][ldsP[i]]);
      }
      asm volatile("s_waitcnt vmcnt(4)" ::: "memory");
    } else {
      asm volatile("s_waitcnt vmcnt(0)" ::: "memory");
    }
    __syncthreads();
#pragma unroll
    for (int ks = 0; ks < 2; ++ks) {
      i32x2 af[8], bfr[4];
#pragma unroll
      for (int rf = 0; rf < 8; ++rf)
        af[rf] = *(const i32x2*)(&sA[cur][aOff[ks][rf]]);
#pragma unroll
      for (int cf = 0; cf < 4; ++cf)
        bfr[cf] = *(const i32x2*)(&sB[cur][bOff[ks][cf]]);
#pragma unroll
      for (int rf = 0; rf < 8; ++rf)
#pragma unroll
        for (int cf = 0; cf < 4; ++cf)
          acc[rf][cf] = mfma8(af[rf], bfr[cf], acc[rf][cf]);
    }
    __syncthreads();
  }

#pragma unroll
  for (int cf = 0; cf < 4; ++cf) {
    float bb = bias[n0 + wc * 64 + cf * 16 + lrow];
#pragma unroll
    for (int rf = 0; rf < 8; ++rf)
#pragma unroll
      for (int r = 0; r < 4; ++r) {
        int row = m0 + wr * 128 + rf * 16 + lseg * 4 + r;
        dst[(size_t)row * 4096 + n0 + wc * 64 + cf * 16 + lrow] = f2fp8(acc[rf][cf][r] + bb);
      }
  }
}

// ---------- k_out8: 128 pairs/block; fp8 gathers/Wc + bf16 Wv + f32 vis ----------
__global__ __launch_bounds__(512, 4) void k_out8(
    const u8* __restrict__ HU, const u8* __restrict__ TU,
    const u8* __restrict__ WcF8, const bf16_t* __restrict__ WvcatT,
    const float* __restrict__ bcv,
    const int* __restrict__ pair_idx, const int* __restrict__ pair_pred,
    const float* __restrict__ vis, const float* __restrict__ freq,
    float* __restrict__ out) {
  // buf layout (28 KB): HU [0,8K) | TU [8K,16K) | Wc [16K,20K) | Wv [20K,28K)
  __shared__ char smem[57344];
  __shared__ int sR0[128], sR1[128];

  const int t = threadIdx.x, wid = t >> 6, l = t & 63;
  const int lrow = l & 15, lseg = l >> 4;
  const int p0 = blockIdx.x * 128;

  if (t < 128) { sR0[t] = pair_idx[(p0 + t) * 2]; sR1[t] = pair_idx[(p0 + t) * 2 + 1]; }
  __syncthreads();

  const u8* srcH; const u8* srcT; int ldsG;
  {
    int row = t >> 2, seg = t & 3;
    int u = seg ^ ((row >> 1) & 3);
    srcH = HU + (size_t)sR0[row] * 4096 + u * 16;
    srcT = TU + (size_t)sR1[row] * 4096 + u * 16;
    ldsG = t * 16;
  }
  const u8* srcWc = nullptr; int ldsWc = 0;
  if (t >= 256) {
    int s = t - 256, col = s >> 2, seg = s & 3;
    int u = seg ^ ((col >> 1) & 3);
    srcWc = WcF8 + (size_t)col * 4096 + u * 16;
    ldsWc = 16384 + s * 16;
  }
  const bf16_t* srcWv; int ldsWv;
  {
    int col = t >> 3, seg = t & 7;
    int u = seg ^ (col & 7);
    srcWv = WvcatT + (size_t)col * 4096 + u * 8;
    ldsWv = 20480 + t * 16;
  }

  const float* vb = vis + (size_t)(p0 + wid * 16 + lrow) * 4096 + lseg * 8;

  const int ra = wid * 16 + lrow;
  int pOff[2];
#pragma unroll
  for (int ks = 0; ks < 2; ++ks) {
    int unit = ks * 2 + (lseg >> 1);
    pOff[ks] = ra * 64 + ((unit ^ ((ra >> 1) & 3)) * 16) + (lseg & 1) * 8;
  }

  f32x4 acc[4];
#pragma unroll
  for (int cf = 0; cf < 4; ++cf) { f32x4 z = {0.f, 0.f, 0.f, 0.f}; acc[cf] = z; }

  auto stage = [&](int tt) {
    const int ke = tt * 64;
    char* b = smem + (tt & 1) * 28672;
    gload16(srcH + ke, b + ldsG);
    gload16(srcT + ke, b + 8192 + ldsG);
    gload16(srcWv + (size_t)ke, b + ldsWv);
    if (t >= 256) gload16(srcWc + ke, b + ldsWc);
  };

  int wcFrag[2][4], wvFrag[2][4];
#pragma unroll
  for (int ks = 0; ks < 2; ++ks)
#pragma unroll
    for (int cf = 0; cf < 4; ++cf) {
      int col = cf * 16 + lrow;
      int unit = (ks * 2 + (lseg >> 1)) ^ ((col >> 1) & 3);
      wcFrag[ks][cf] = 16384 + col * 64 + unit * 16 + (lseg & 1) * 8;
      wvFrag[ks][cf] = 20480 + col * 128 + (((ks * 4 + lseg) ^ (col & 7)) * 16);
    }

  stage(0);

#pragma unroll 1
  for (int tt = 0; tt < 64; ++tt) {
    const char* b = smem + (tt & 1) * 28672;
    const int kb = tt * 64;
    f32x4 vv[4];
#pragma unroll
    for (int ks = 0; ks < 2; ++ks) {
      vv[ks * 2 + 0] = *(const f32x4*)(vb + kb + ks * 32);
      vv[ks * 2 + 1] = *(const f32x4*)(vb + kb + ks * 32 + 4);
    }
    __builtin_amdgcn_sched_barrier(0);
    if (tt < 63) {
      stage(tt + 1);
      __builtin_amdgcn_sched_barrier(0);
      // FIFO: stage(tt)[8] , vv[4] , stage(tt+1)[8] = 20 outstanding.
      // vmcnt(8) retires exactly stage(tt)+vv, leaves stage(tt+1) in flight.
      asm volatile("s_waitcnt vmcnt(8)" ::: "memory");
    } else {
      asm volatile("s_waitcnt vmcnt(0)" ::: "memory");
    }
    __syncthreads();
#pragma unroll
    for (int ks = 0; ks < 2; ++ks) {
      i32x2 hv = *(const i32x2*)(b + pOff[ks]);
      i32x2 tv = *(const i32x2*)(b + 8192 + pOff[ks]);
      int h0 = hv[0], h1 = hv[1], t0 = tv[0], t1 = tv[1];
      const float us = 0.015625f;   // 1/64
      float f0 = fmaxf(__builtin_amdgcn_cvt_f32_fp8(h0, 0) + __builtin_amdgcn_cvt_f32_fp8(t0, 0), 0.f) * us;
      float f1 = fmaxf(__builtin_amdgcn_cvt_f32_fp8(h0, 1) + __builtin_amdgcn_cvt_f32_fp8(t0, 1), 0.f) * us;
      float f2 = fmaxf(__builtin_amdgcn_cvt_f32_fp8(h0, 2) + __builtin_amdgcn_cvt_f32_fp8(t0, 2), 0.f) * us;
      float f3 = fmaxf(__builtin_amdgcn_cvt_f32_fp8(h0, 3) + __builtin_amdgcn_cvt_f32_fp8(t0, 3), 0.f) * us;
      float f4 = fmaxf(__builtin_amdgcn_cvt_f32_fp8(h1, 0) + __builtin_amdgcn_cvt_f32_fp8(t1, 0), 0.f) * us;
      float f5 = fmaxf(__builtin_amdgcn_cvt_f32_fp8(h1, 1) + __builtin_amdgcn_cvt_f32_fp8(t1, 1), 0.f) * us;
      float f6 = fmaxf(__builtin_amdgcn_cvt_f32_fp8(h1, 2) + __builtin_amdgcn_cvt_f32_fp8(t1, 2), 0.f) * us;
      float f7 = fmaxf(__builtin_amdgcn_cvt_f32_fp8(h1, 3) + __builtin_amdgcn_cvt_f32_fp8(t1, 3), 0.f) * us;
      i32x2 pa;
      {
        int w0 = __builtin_amdgcn_cvt_pk_fp8_f32(f0, f1, 0, false);
        w0 = __builtin_amdgcn_cvt_pk_fp8_f32(f2, f3, w0, true);
        int w1 = __builtin_amdgcn_cvt_pk_fp8_f32(f4, f5, 0, false);
        w1 = __builtin_amdgcn_cvt_pk_fp8_f32(f6, f7, w1, true);
        pa[0] = w0; pa[1] = w1;
      }
#pragma unroll
      for (int cf = 0; cf < 4; ++cf) {
        i32x2 bw = *(const i32x2*)(b + wcFrag[ks][cf]);
        acc[cf] = mfma8(pa, bw, acc[cf]);
      }
      f32x4 v0 = vv[ks * 2 + 0], v1 = vv[ks * 2 + 1];
      bf16x8 ag;
      ag[0] = (bf16_t)v0[0]; ag[1] = (bf16_t)v0[1]; ag[2] = (bf16_t)v0[2]; ag[3] = (bf16_t)v0[3];
      ag[4] = (bf16_t)v1[0]; ag[5] = (bf16_t)v1[1]; ag[6] = (bf16_t)v1[2]; ag[7] = (bf16_t)v1[3];
#pragma unroll
      for (int cf = 0; cf < 4; ++cf) {
        bf16x8 bw = *(const bf16x8*)(b + wvFrag[ks][cf]);
        acc[cf] = mfma16(ag, bw, acc[cf]);
      }
    }
    __syncthreads();
  }

  // epilogue
  float* sF = (float*)smem;
#pragma unroll
  for (int cf = 0; cf < 4; ++cf) {
    float bb = bcv[cf * 16 + lrow];
#pragma unroll
    for (int r = 0; r < 4; ++r) {
      int row = wid * 16 + lseg * 4 + r;
      sF[row * 64 + cf * 16 + lrow] = acc[cf][r] + bb;
    }
  }
  __syncthreads();
  if (t < 128) {
    int p = p0 + t;
    const float* f = freq + ((size_t)pair_pred[p * 2] * 151 + pair_pred[p * 2 + 1]) * 51;
    const float* rowv = sF + t * 64;
    float e1 = 0.f, e2 = 0.f, e3 = 0.f;
#pragma unroll
    for (int c = 0; c < 15; ++c) {
      float fb = f[GEO_c[c]]; e1 += expf(fb);
      out[(size_t)p * 15 + c] = rowv[c] + fb;
    }
#pragma unroll
    for (int c = 0; c < 11; ++c) {
      float fb = f[POS_c[c]]; e2 += expf(fb);
      out[491520 + (size_t)p * 11 + c] = rowv[15 + c] + fb;
    }
#pragma unroll
    for (int c = 0; c < 24; ++c) {
      float fb = f[SEM_c[c]]; e3 += expf(fb);
      out[851968 + (size_t)p * 24 + c] = rowv[26 + c] + fb;
    }
    out[1638400 + (size_t)p * 4 + 0] = rowv[50] + f[0];
    out[1638400 + (size_t)p * 4 + 1] = rowv[51] + logf(e1);
    out[1638400 + (size_t)p * 4 + 2] = rowv[52] + logf(e2);
    out[1638400 + (size_t)p * 4 + 3] = rowv[53] + logf(e3);
  }
}

extern "C" void kernel_launch(void* const* d_in, const int* in_sizes, int n_in,
                              void* d_out, int out_size, void* d_ws, size_t ws_size,
                              hipStream_t stream) {
  const float* edge_ctx  = (const float*)d_in[0];
  const int*   pair_idx  = (const int*)d_in[1];
  const float* vis_rep   = (const float*)d_in[2];
  const int*   pair_pred = (const int*)d_in[3];
  const float* Wpe = (const float*)d_in[4];
  const float* bpe = (const float*)d_in[5];
  const float* Wpc = (const float*)d_in[6];
  const float* bpc = (const float*)d_in[7];
  const float* Wc1 = (const float*)d_in[8];  const float* bc1 = (const float*)d_in[9];
  const float* Wc2 = (const float*)d_in[10]; const float* bc2 = (const float*)d_in[11];
  const float* Wc3 = (const float*)d_in[12]; const float* bc3 = (const float*)d_in[13];
  const float* Wcs = (const float*)d_in[14]; const float* bcs = (const float*)d_in[15];
  const float* Wv1 = (const float*)d_in[16]; const float* bv1 = (const float*)d_in[17];
  const float* Wv2 = (const float*)d_in[18]; const float* bv2 = (const float*)d_in[19];
  const float* Wv3 = (const float*)d_in[20]; const float* bv3 = (const float*)d_in[21];
  const float* Wvs = (const float*)d_in[22]; const float* bvs = (const float*)d_in[23];
  const float* freq = (const float*)d_in[24];
  float* out = (float*)d_out;

  char* ws = (char*)d_ws;
  bf16_t* WpcT   = (bf16_t*)(ws + 0);           //  8388608
  u8*     W1F8   = (u8*)(ws + 8388608);         //  2097152
  u8*     W2F8   = (u8*)(ws + 10485760);        //  2097152
  u8*     ecf8   = (u8*)(ws + 12582912);        //  4194304
  u8*     WcF8   = (u8*)(ws + 16777216);        //   262144
  bf16_t* WvcatT = (bf16_t*)(ws + 17039360);    //   524288
  float*  bcv    = (float*)(ws + 17563648);     //     4096
  float*  b12    = (float*)(ws + 17567744);     //    32768
  u8*     HU     = (u8*)(ws + 17600512);        // 33554432
  u8*     TU     = (u8*)(ws + 51154944);        // 33554432  -> end 84709376

  k_transpose<<<dim3(64, 16), 256, 0, stream>>>(Wpc, WpcT, 1024, 4096);
  k_pack_cat<<<64, 256, 0, stream>>>(Wc1, Wc2, Wc3, Wcs, Wv1, Wv2, Wv3, Wvs,
                                     bc1, bc2, bc3, bcs, bv1, bv2, bv3, bvs,
                                     WcF8, WvcatT, bcv);
  k_ec8<<<2048, 256, 0, stream>>>(edge_ctx, ecf8);
  k_w12<<<dim3(4, 32, 2), 256, 0, stream>>>(WpcT, Wpe, W1F8, W2F8);
  k_bias<<<1024, 256, 0, stream>>>(WpcT, bpe, bpc, b12);
  k_ht6<<<dim3(16, 32, 2), 512, 0, stream>>>(ecf8, W1F8, W2F8, b12, HU, TU);
  k_out8<<<256, 512, 0, stream>>>(HU, TU, WcF8, WvcatT, bcv,
                                  pair_idx, pair_pred, vis_rep, freq, out);
}

// Round 16
// 328.315 us; speedup vs baseline: 1.8855x; 1.0066x over previous
//
#include <hip/hip_runtime.h>
#include <hip/hip_bf16.h>

typedef __bf16 bf16_t;
typedef __bf16 bf16x8 __attribute__((ext_vector_type(8)));
typedef __bf16 bf16x4 __attribute__((ext_vector_type(4)));
typedef float f32x4 __attribute__((ext_vector_type(4)));
typedef int i32x2 __attribute__((ext_vector_type(2)));
typedef unsigned char u8;

#define DI __device__ __forceinline__

DI f32x4 mfma16(bf16x8 a, bf16x8 b, f32x4 c) {
  return __builtin_amdgcn_mfma_f32_16x16x32_bf16(a, b, c, 0, 0, 0);
}
DI f32x4 mfma8(i32x2 a, i32x2 b, f32x4 c) {
  return __builtin_amdgcn_mfma_f32_16x16x32_fp8_fp8(
      __builtin_bit_cast(long, a), __builtin_bit_cast(long, b), c, 0, 0, 0);
}
DI void gload16(const void* g, void* l) {
  __builtin_amdgcn_global_load_lds(
      (const __attribute__((address_space(1))) unsigned int*)g,
      (__attribute__((address_space(3))) unsigned int*)l, 16, 0, 0);
}
DI u8 f2fp8(float x) {
  return (u8)(__builtin_amdgcn_cvt_pk_fp8_f32(x, x, 0, false) & 0xff);
}

__constant__ int GEO_c[15] = {1,2,3,4,5,6,8,10,22,23,29,31,32,33,43};
__constant__ int POS_c[11] = {9,16,17,20,27,30,36,42,48,49,50};
__constant__ int SEM_c[24] = {7,11,12,13,14,15,18,19,21,24,25,26,28,34,35,37,38,39,40,41,44,45,46,47};

// ---------- prep: transpose f32 Wpc [1024][4096] -> bf16 WpcT [4096][1024] ----------
__global__ void k_transpose(const float* __restrict__ src, bf16_t* __restrict__ dst,
                            int K, int N) {
  __shared__ float s[64][65];
  int n0 = blockIdx.x * 64, k0 = blockIdx.y * 64;
  int t = threadIdx.x;
#pragma unroll
  for (int i = 0; i < 4; ++i) {
    int idx = t + i * 256; int kr = idx >> 4, seg = idx & 15;
    float4 v = *(const float4*)(src + (size_t)(k0 + kr) * N + n0 + seg * 4);
    s[kr][seg * 4 + 0] = v.x; s[kr][seg * 4 + 1] = v.y;
    s[kr][seg * 4 + 2] = v.z; s[kr][seg * 4 + 3] = v.w;
  }
  __syncthreads();
#pragma unroll
  for (int i = 0; i < 4; ++i) {
    int idx = t + i * 256; int nr = idx >> 4, seg = idx & 15;
    bf16x4 h;
    h[0] = (bf16_t)s[seg * 4 + 0][nr]; h[1] = (bf16_t)s[seg * 4 + 1][nr];
    h[2] = (bf16_t)s[seg * 4 + 2][nr]; h[3] = (bf16_t)s[seg * 4 + 3][nr];
    *(bf16x4*)(dst + (size_t)(n0 + nr) * K + k0 + seg * 4) = h;
  }
}

// ---------- prep: pack Wc* (fp8) / Wv* (bf16) into [64][4096], bcv ----------
DI void cat_map(int j, int& which, int& sub, int& nc) {
  if (j < 15)      { which = 0; sub = j;      nc = 15; }
  else if (j < 26) { which = 1; sub = j - 15; nc = 11; }
  else if (j < 50) { which = 2; sub = j - 26; nc = 24; }
  else if (j < 54) { which = 3; sub = j - 50; nc = 4;  }
  else             { which = 4; sub = 0;      nc = 1;  }
}

__global__ void k_pack_cat(const float* __restrict__ Wc1, const float* __restrict__ Wc2,
                           const float* __restrict__ Wc3, const float* __restrict__ Wcs,
                           const float* __restrict__ Wv1, const float* __restrict__ Wv2,
                           const float* __restrict__ Wv3, const float* __restrict__ Wvs,
                           const float* __restrict__ bc1, const float* __restrict__ bc2,
                           const float* __restrict__ bc3, const float* __restrict__ bcs,
                           const float* __restrict__ bv1, const float* __restrict__ bv2,
                           const float* __restrict__ bv3, const float* __restrict__ bvs,
                           u8* __restrict__ WcF8, bf16_t* __restrict__ WvcatT,
                           float* __restrict__ bcv) {
  int j = blockIdx.x, t = threadIdx.x;
  int which, sub, nc; cat_map(j, which, sub, nc);
  const float* Wc = which == 0 ? Wc1 : which == 1 ? Wc2 : which == 2 ? Wc3 : Wcs;
  const float* Wv = which == 0 ? Wv1 : which == 1 ? Wv2 : which == 2 ? Wv3 : Wvs;
  for (int i = 0; i < 16; ++i) {
    int k = t + i * 256;
    float vc = 0.f, vv = 0.f;
    if (which < 4) { vc = Wc[(size_t)k * nc + sub]; vv = Wv[(size_t)k * nc + sub]; }
    WcF8[(size_t)j * 4096 + k] = f2fp8(vc);
    WvcatT[(size_t)j * 4096 + k] = (bf16_t)vv;
  }
  if (t == 0) {
    float b = 0.f;
    if (which < 4) {
      const float* bc = which == 0 ? bc1 : which == 1 ? bc2 : which == 2 ? bc3 : bcs;
      const float* bv = which == 0 ? bv1 : which == 1 ? bv2 : which == 2 ? bv3 : bvs;
      b = bc[sub] + bv[sub];
    }
    bcv[j] = b;
  }
}

// ---------- prep: ec f32 -> ecf8 ----------
__global__ __launch_bounds__(256) void k_ec8(const float* __restrict__ ec,
                                             u8* __restrict__ ecf8) {
  size_t i = ((size_t)blockIdx.x * 256 + threadIdx.x) * 8;
  float4 a = *(const float4*)(ec + i), b = *(const float4*)(ec + i + 4);
  int w0 = __builtin_amdgcn_cvt_pk_fp8_f32(a.x, a.y, 0, false);
  w0 = __builtin_amdgcn_cvt_pk_fp8_f32(a.z, a.w, w0, true);
  int w1 = __builtin_amdgcn_cvt_pk_fp8_f32(b.x, b.y, 0, false);
  w1 = __builtin_amdgcn_cvt_pk_fp8_f32(b.z, b.w, w1, true);
  i32x2 p; p[0] = w0; p[1] = w1;
  *(i32x2*)(ecf8 + i) = p;
}

// ---------- prep: W1/W2 fp8 (x64 scale) ----------
__global__ __launch_bounds__(256) void k_w12(const bf16_t* __restrict__ WpcT,
                                             const float* __restrict__ Wpe,
                                             u8* __restrict__ W1F8,
                                             u8* __restrict__ W2F8) {
  __shared__ bf16_t sA[128 * 64];
  __shared__ bf16_t sB[128 * 64];
  const int t = threadIdx.x, w = t >> 6, l = t & 63;
  const int lrow = l & 15, lkB = (l >> 4) << 4;
  const int k0 = blockIdx.x * 128, n0 = blockIdx.y * 128;
  const int joff = blockIdx.z * 512;
  u8* dst = blockIdx.z ? W2F8 : W1F8;

  f32x4 acc[2][8];
#pragma unroll
  for (int rf = 0; rf < 2; ++rf)
#pragma unroll
    for (int cf = 0; cf < 8; ++cf) { f32x4 z = {0.f, 0.f, 0.f, 0.f}; acc[rf][cf] = z; }

  for (int jj = 0; jj < 512; jj += 64) {
    __syncthreads();
#pragma unroll
    for (int i = 0; i < 4; ++i) {
      int row = (t >> 3) + (i << 5), seg = t & 7;
      bf16x8 v = *(const bf16x8*)(WpcT + (size_t)(n0 + row) * 1024 + joff + jj + seg * 8);
      *(bf16x8*)((char*)sA + (row << 7) + ((seg << 4) ^ ((row & 7) << 4))) = v;
    }
#pragma unroll
    for (int i = 0; i < 8; ++i) {
      int idx = t + i * 256; int row = idx >> 4, seg = idx & 15;
      float4 v = *(const float4*)(Wpe + (size_t)(k0 + row) * 1024 + joff + jj + seg * 4);
      bf16x4 h; h[0] = (bf16_t)v.x; h[1] = (bf16_t)v.y; h[2] = (bf16_t)v.z; h[3] = (bf16_t)v.w;
      *(bf16x4*)((char*)sB + (row << 7) + ((seg << 3) ^ ((row & 7) << 4))) = h;
    }
    __syncthreads();
#pragma unroll
    for (int ks = 0; ks < 2; ++ks) {
      bf16x8 af[2], bfr[8];
#pragma unroll
      for (int rf = 0; rf < 2; ++rf) {
        int row = w * 32 + rf * 16 + lrow;
        af[rf] = *(const bf16x8*)((const char*)sA + (row << 7) + (((ks << 6) | lkB) ^ ((row & 7) << 4)));
      }
#pragma unroll
      for (int cf = 0; cf < 8; ++cf) {
        int col = cf * 16 + lrow;
        bfr[cf] = *(const bf16x8*)((const char*)sB + (col << 7) + (((ks << 6) | lkB) ^ ((col & 7) << 4)));
      }
#pragma unroll
      for (int rf = 0; rf < 2; ++rf)
#pragma unroll
        for (int cf = 0; cf < 8; ++cf)
          acc[rf][cf] = mfma16(af[rf], bfr[cf], acc[rf][cf]);
    }
  }
#pragma unroll
  for (int cf = 0; cf < 8; ++cf)
#pragma unroll
    for (int rf = 0; rf < 2; ++rf)
#pragma unroll
      for (int r = 0; r < 4; ++r) {
        int nrow = n0 + w * 32 + rf * 16 + ((l >> 4) << 2) + r;
        dst[(size_t)nrow * 512 + k0 + cf * 16 + lrow] = f2fp8(acc[rf][cf][r] * 64.f);
      }
}

// ---------- prep: b12 (x64 scaled) ----------
__global__ __launch_bounds__(256) void k_bias(const bf16_t* __restrict__ WpcT,
                                              const float* __restrict__ bpe,
                                              const float* __restrict__ bpc,
                                              float* __restrict__ b12) {
  int w = threadIdx.x >> 6, l = threadIdx.x & 63;
  int n = blockIdx.x * 4 + w;
  const bf16_t* r = WpcT + (size_t)n * 1024;
  bf16x8 v1 = *(const bf16x8*)(r + l * 8);
  bf16x8 v2 = *(const bf16x8*)(r + 512 + l * 8);
  float s1 = 0.f, s2 = 0.f;
#pragma unroll
  for (int e = 0; e < 8; ++e) {
    s1 += (float)v1[e] * bpe[l * 8 + e];
    s2 += (float)v2[e] * bpe[512 + l * 8 + e];
  }
#pragma unroll
  for (int off = 32; off; off >>= 1) {
    s1 += __shfl_down(s1, off);
    s2 += __shfl_down(s2, off);
  }
  if (l == 0) { b12[n] = 64.f * (s1 + bpc[n]); b12[4096 + n] = 64.f * s2; }
}

// ---------- k_ht6: HU/TU(fp8, x64) = ecf8 @ W{1,2}F8 + b12, fp8 MFMA ----------
__global__ __launch_bounds__(512, 1) void k_ht6(const u8* __restrict__ ecf8,
                                                const u8* __restrict__ W1F8,
                                                const u8* __restrict__ W2F8,
                                                const float* __restrict__ b12,
                                                u8* __restrict__ HU,
                                                u8* __restrict__ TU) {
  __shared__ u8 sA[2][16384];
  __shared__ u8 sB[2][16384];
  const int t = threadIdx.x, wid = t >> 6, l = t & 63;
  const int lrow = l & 15, lseg = l >> 4;
  const int wr = wid >> 2, wc = wid & 3;
  const int n0 = blockIdx.x * 256, m0 = blockIdx.y * 256, z = blockIdx.z;
  const u8* Bw = z ? W2F8 : W1F8;
  const float* bias = b12 + z * 4096;
  u8* dst = z ? TU : HU;

  const u8* gA[2]; const u8* gB[2]; int ldsP[2];
#pragma unroll
  for (int i = 0; i < 2; ++i) {
    int slot = t + i * 512, row = slot >> 2, seg = slot & 3;
    int u = seg ^ ((row >> 1) & 3);
    gA[i] = ecf8 + (size_t)(m0 + row) * 512 + u * 16;
    gB[i] = Bw + (size_t)(n0 + row) * 512 + u * 16;
    ldsP[i] = slot * 16;
  }

  int aOff[2][8], bOff[2][4];
#pragma unroll
  for (int ks = 0; ks < 2; ++ks) {
#pragma unroll
    for (int rf = 0; rf < 8; ++rf) {
      int row = wr * 128 + rf * 16 + lrow;
      aOff[ks][rf] = row * 64 + (((ks * 2 + (lseg >> 1)) ^ ((row >> 1) & 3)) * 16) + (lseg & 1) * 8;
    }
#pragma unroll
    for (int cf = 0; cf < 4; ++cf) {
      int col = wc * 64 + cf * 16 + lrow;
      bOff[ks][cf] = col * 64 + (((ks * 2 + (lseg >> 1)) ^ ((col >> 1) & 3)) * 16) + (lseg & 1) * 8;
    }
  }

  f32x4 acc[8][4];
#pragma unroll
  for (int rf = 0; rf < 8; ++rf)
#pragma unroll
    for (int cf = 0; cf < 4; ++cf) { f32x4 zz = {0.f, 0.f, 0.f, 0.f}; acc[rf][cf] = zz; }

#pragma unroll
  for (int i = 0; i < 2; ++i) { gload16(gA[i], &sA[0][ldsP[i]]); gload16(gB[i], &sB[0][ldsP[i]]); }

#pragma unroll 1
  for (int tt = 0; tt < 8; ++tt) {
    const int cur = tt & 1;
    if (tt < 7) {
      const int kk = (tt + 1) * 64;
#pragma unroll
      for (int i = 0; i < 2; ++i) {
        gload16(gA[i] + kk, &sA[cur ^ 1][ldsP[i]]);
        gload16(gB[i] + kk, &sB[cur ^ 1][ldsP[i]]);
      }
      asm volatile("s_waitcnt vmcnt(4)" ::: "memory");
    } else {
      asm volatile("s_waitcnt vmcnt(0)" ::: "memory");
    }
    __syncthreads();
#pragma unroll
    for (int ks = 0; ks < 2; ++ks) {
      i32x2 af[8], bfr[4];
#pragma unroll
      for (int rf = 0; rf < 8; ++rf)
        af[rf] = *(const i32x2*)(&sA[cur][aOff[ks][rf]]);
#pragma unroll
      for (int cf = 0; cf < 4; ++cf)
        bfr[cf] = *(const i32x2*)(&sB[cur][bOff[ks][cf]]);
#pragma unroll
      for (int rf = 0; rf < 8; ++rf)
#pragma unroll
        for (int cf = 0; cf < 4; ++cf)
          acc[rf][cf] = mfma8(af[rf], bfr[cf], acc[rf][cf]);
    }
    __syncthreads();
  }

#pragma unroll
  for (int cf = 0; cf < 4; ++cf) {
    float bb = bias[n0 + wc * 64 + cf * 16 + lrow];
#pragma unroll
    for (int rf = 0; rf < 8; ++rf)
#pragma unroll
      for (int r = 0; r < 4; ++r) {
        int row = m0 + wr * 128 + rf * 16 + lseg * 4 + r;
        dst[(size_t)row * 4096 + n0 + wc * 64 + cf * 16 + lrow] = f2fp8(acc[rf][cf][r] + bb);
      }
  }
}

// ---------- k_out9: split-K=2; 512 blocks x (128 pairs, K=2048); 2 blocks/CU ----------
__global__ __launch_bounds__(512, 4) void k_out9(
    const u8* __restrict__ HU, const u8* __restrict__ TU,
    const u8* __restrict__ WcF8, const bf16_t* __restrict__ WvcatT,
    const int* __restrict__ pair_idx, const float* __restrict__ vis,
    float* __restrict__ pacc) {
  // buf layout (28 KB): HU [0,8K) | TU [8K,16K) | Wc [16K,20K) | Wv [20K,28K)
  __shared__ char smem[57344];
  __shared__ int sR0[128], sR1[128];

  const int t = threadIdx.x, wid = t >> 6, l = t & 63;
  const int lrow = l & 15, lseg = l >> 4;
  const int p0 = blockIdx.x * 128;
  const int c0 = blockIdx.y * 32;          // K-half: chunks c0..c0+31

  if (t < 128) { sR0[t] = pair_idx[(p0 + t) * 2]; sR1[t] = pair_idx[(p0 + t) * 2 + 1]; }
  __syncthreads();

  const u8* srcH; const u8* srcT; int ldsG;
  {
    int row = t >> 2, seg = t & 3;
    int u = seg ^ ((row >> 1) & 3);
    srcH = HU + (size_t)sR0[row] * 4096 + u * 16;
    srcT = TU + (size_t)sR1[row] * 4096 + u * 16;
    ldsG = t * 16;
  }
  const u8* srcWc = nullptr; int ldsWc = 0;
  if (t >= 256) {
    int s = t - 256, col = s >> 2, seg = s & 3;
    int u = seg ^ ((col >> 1) & 3);
    srcWc = WcF8 + (size_t)col * 4096 + u * 16;
    ldsWc = 16384 + s * 16;
  }
  const bf16_t* srcWv; int ldsWv;
  {
    int col = t >> 3, seg = t & 7;
    int u = seg ^ (col & 7);
    srcWv = WvcatT + (size_t)col * 4096 + u * 8;
    ldsWv = 20480 + t * 16;
  }

  const float* vb = vis + (size_t)(p0 + wid * 16 + lrow) * 4096 + lseg * 8;

  const int ra = wid * 16 + lrow;
  int pOff[2];
#pragma unroll
  for (int ks = 0; ks < 2; ++ks) {
    int unit = ks * 2 + (lseg >> 1);
    pOff[ks] = ra * 64 + ((unit ^ ((ra >> 1) & 3)) * 16) + (lseg & 1) * 8;
  }

  f32x4 acc[4];
#pragma unroll
  for (int cf = 0; cf < 4; ++cf) { f32x4 z = {0.f, 0.f, 0.f, 0.f}; acc[cf] = z; }

  auto stage = [&](int tt) {               // tt = local chunk 0..31
    const int ke = (c0 + tt) * 64;
    char* b = smem + (tt & 1) * 28672;
    gload16(srcH + ke, b + ldsG);
    gload16(srcT + ke, b + 8192 + ldsG);
    gload16(srcWv + (size_t)ke, b + ldsWv);
    if (t >= 256) gload16(srcWc + ke, b + ldsWc);
  };

  int wcFrag[2][4], wvFrag[2][4];
#pragma unroll
  for (int ks = 0; ks < 2; ++ks)
#pragma unroll
    for (int cf = 0; cf < 4; ++cf) {
      int col = cf * 16 + lrow;
      int unit = (ks * 2 + (lseg >> 1)) ^ ((col >> 1) & 3);
      wcFrag[ks][cf] = 16384 + col * 64 + unit * 16 + (lseg & 1) * 8;
      wvFrag[ks][cf] = 20480 + col * 128 + (((ks * 4 + lseg) ^ (col & 7)) * 16);
    }

  stage(0);

#pragma unroll 1
  for (int tt = 0; tt < 32; ++tt) {
    const char* b = smem + (tt & 1) * 28672;
    const int kb = (c0 + tt) * 64;
    f32x4 vv[4];
#pragma unroll
    for (int ks = 0; ks < 2; ++ks) {
      vv[ks * 2 + 0] = *(const f32x4*)(vb + kb + ks * 32);
      vv[ks * 2 + 1] = *(const f32x4*)(vb + kb + ks * 32 + 4);
    }
    __builtin_amdgcn_sched_barrier(0);
    if (tt < 31) {
      stage(tt + 1);
      __builtin_amdgcn_sched_barrier(0);
      // FIFO: stage(tt)[8], vv[4], stage(tt+1)[8] = 20; vmcnt(8) retires stage(tt)+vv
      asm volatile("s_waitcnt vmcnt(8)" ::: "memory");
    } else {
      asm volatile("s_waitcnt vmcnt(0)" ::: "memory");
    }
    __syncthreads();
#pragma unroll
    for (int ks = 0; ks < 2; ++ks) {
      i32x2 hv = *(const i32x2*)(b + pOff[ks]);
      i32x2 tv = *(const i32x2*)(b + 8192 + pOff[ks]);
      int h0 = hv[0], h1 = hv[1], t0 = tv[0], t1 = tv[1];
      const float us = 0.015625f;   // 1/64
      float f0 = fmaxf(__builtin_amdgcn_cvt_f32_fp8(h0, 0) + __builtin_amdgcn_cvt_f32_fp8(t0, 0), 0.f) * us;
      float f1 = fmaxf(__builtin_amdgcn_cvt_f32_fp8(h0, 1) + __builtin_amdgcn_cvt_f32_fp8(t0, 1), 0.f) * us;
      float f2 = fmaxf(__builtin_amdgcn_cvt_f32_fp8(h0, 2) + __builtin_amdgcn_cvt_f32_fp8(t0, 2), 0.f) * us;
      float f3 = fmaxf(__builtin_amdgcn_cvt_f32_fp8(h0, 3) + __builtin_amdgcn_cvt_f32_fp8(t0, 3), 0.f) * us;
      float f4 = fmaxf(__builtin_amdgcn_cvt_f32_fp8(h1, 0) + __builtin_amdgcn_cvt_f32_fp8(t1, 0), 0.f) * us;
      float f5 = fmaxf(__builtin_amdgcn_cvt_f32_fp8(h1, 1) + __builtin_amdgcn_cvt_f32_fp8(t1, 1), 0.f) * us;
      float f6 = fmaxf(__builtin_amdgcn_cvt_f32_fp8(h1, 2) + __builtin_amdgcn_cvt_f32_fp8(t1, 2), 0.f) * us;
      float f7 = fmaxf(__builtin_amdgcn_cvt_f32_fp8(h1, 3) + __builtin_amdgcn_cvt_f32_fp8(t1, 3), 0.f) * us;
      i32x2 pa;
      {
        int w0 = __builtin_amdgcn_cvt_pk_fp8_f32(f0, f1, 0, false);
        w0 = __builtin_amdgcn_cvt_pk_fp8_f32(f2, f3, w0, true);
        int w1 = __builtin_amdgcn_cvt_pk_fp8_f32(f4, f5, 0, false);
        w1 = __builtin_amdgcn_cvt_pk_fp8_f32(f6, f7, w1, true);
        pa[0] = w0; pa[1] = w1;
      }
#pragma unroll
      for (int cf = 0; cf < 4; ++cf) {
        i32x2 bw = *(const i32x2*)(b + wcFrag[ks][cf]);
        acc[cf] = mfma8(pa, bw, acc[cf]);
      }
      f32x4 v0 = vv[ks * 2 + 0], v1 = vv[ks * 2 + 1];
      bf16x8 ag;
      ag[0] = (bf16_t)v0[0]; ag[1] = (bf16_t)v0[1]; ag[2] = (bf16_t)v0[2]; ag[3] = (bf16_t)v0[3];
      ag[4] = (bf16_t)v1[0]; ag[5] = (bf16_t)v1[1]; ag[6] = (bf16_t)v1[2]; ag[7] = (bf16_t)v1[3];
#pragma unroll
      for (int cf = 0; cf < 4; ++cf) {
        bf16x8 bw = *(const bf16x8*)(b + wvFrag[ks][cf]);
        acc[cf] = mfma16(ag, bw, acc[cf]);
      }
    }
    __syncthreads();
  }

  // write partial acc (no bias/epilogue here)
  float* pa = pacc + ((size_t)blockIdx.y * 256 + blockIdx.x) * 128 * 64;
#pragma unroll
  for (int cf = 0; cf < 4; ++cf)
#pragma unroll
    for (int r = 0; r < 4; ++r) {
      int row = wid * 16 + lseg * 4 + r;
      pa[row * 64 + cf * 16 + lrow] = acc[cf][r];
    }
}

// ---------- k_fin: sum 2 partials + bcv + freq epilogue ----------
__global__ __launch_bounds__(256) void k_fin(const float* __restrict__ pacc,
                                             const float* __restrict__ bcv,
                                             const int* __restrict__ pair_pred,
                                             const float* __restrict__ freq,
                                             float* __restrict__ out) {
  int p = blockIdx.x * 256 + threadIdx.x;
  int g = p >> 7, row = p & 127;
  const float* a0 = pacc + ((size_t)g * 128 + row) * 64;
  const float* a1 = pacc + ((size_t)(256 + g) * 128 + row) * 64;
  const float* f = freq + ((size_t)pair_pred[p * 2] * 151 + pair_pred[p * 2 + 1]) * 51;
  float e1 = 0.f, e2 = 0.f, e3 = 0.f;
#pragma unroll
  for (int c = 0; c < 15; ++c) {
    float fb = f[GEO_c[c]]; e1 += expf(fb);
    out[(size_t)p * 15 + c] = a0[c] + a1[c] + bcv[c] + fb;
  }
#pragma unroll
  for (int c = 0; c < 11; ++c) {
    float fb = f[POS_c[c]]; e2 += expf(fb);
    out[491520 + (size_t)p * 11 + c] = a0[15 + c] + a1[15 + c] + bcv[15 + c] + fb;
  }
#pragma unroll
  for (int c = 0; c < 24; ++c) {
    float fb = f[SEM_c[c]]; e3 += expf(fb);
    out[851968 + (size_t)p * 24 + c] = a0[26 + c] + a1[26 + c] + bcv[26 + c] + fb;
  }
  out[1638400 + (size_t)p * 4 + 0] = a0[50] + a1[50] + bcv[50] + f[0];
  out[1638400 + (size_t)p * 4 + 1] = a0[51] + a1[51] + bcv[51] + logf(e1);
  out[1638400 + (size_t)p * 4 + 2] = a0[52] + a1[52] + bcv[52] + logf(e2);
  out[1638400 + (size_t)p * 4 + 3] = a0[53] + a1[53] + bcv[53] + logf(e3);
}

extern "C" void kernel_launch(void* const* d_in, const int* in_sizes, int n_in,
                              void* d_out, int out_size, void* d_ws, size_t ws_size,
                              hipStream_t stream) {
  const float* edge_ctx  = (const float*)d_in[0];
  const int*   pair_idx  = (const int*)d_in[1];
  const float* vis_rep   = (const float*)d_in[2];
  const int*   pair_pred = (const int*)d_in[3];
  const float* Wpe = (const float*)d_in[4];
  const float* bpe = (const float*)d_in[5];
  const float* Wpc = (const float*)d_in[6];
  const float* bpc = (const float*)d_in[7];
  const float* Wc1 = (const float*)d_in[8];  const float* bc1 = (const float*)d_in[9];
  const float* Wc2 = (const float*)d_in[10]; const float* bc2 = (const float*)d_in[11];
  const float* Wc3 = (const float*)d_in[12]; const float* bc3 = (const float*)d_in[13];
  const float* Wcs = (const float*)d_in[14]; const float* bcs = (const float*)d_in[15];
  const float* Wv1 = (const float*)d_in[16]; const float* bv1 = (const float*)d_in[17];
  const float* Wv2 = (const float*)d_in[18]; const float* bv2 = (const float*)d_in[19];
  const float* Wv3 = (const float*)d_in[20]; const float* bv3 = (const float*)d_in[21];
  const float* Wvs = (const float*)d_in[22]; const float* bvs = (const float*)d_in[23];
  const float* freq = (const float*)d_in[24];
  float* out = (float*)d_out;

  char* ws = (char*)d_ws;
  // prep region [0,16MB) -> dead before k_out9; pacc aliases it.
  bf16_t* WpcT   = (bf16_t*)(ws + 0);           //  8388608
  u8*     W1F8   = (u8*)(ws + 8388608);         //  2097152
  u8*     W2F8   = (u8*)(ws + 10485760);        //  2097152
  u8*     ecf8   = (u8*)(ws + 12582912);        //  4194304
  float*  pacc   = (float*)(ws + 0);            // 16777216 (alias)
  u8*     WcF8   = (u8*)(ws + 16777216);        //   262144
  bf16_t* WvcatT = (bf16_t*)(ws + 17039360);    //   524288
  float*  bcv    = (float*)(ws + 17563648);     //     4096
  float*  b12    = (float*)(ws + 17567744);     //    32768
  u8*     HU     = (u8*)(ws + 17600512);        // 33554432
  u8*     TU     = (u8*)(ws + 51154944);        // 33554432  -> end 84709376

  k_transpose<<<dim3(64, 16), 256, 0, stream>>>(Wpc, WpcT, 1024, 4096);
  k_pack_cat<<<64, 256, 0, stream>>>(Wc1, Wc2, Wc3, Wcs, Wv1, Wv2, Wv3, Wvs,
                                     bc1, bc2, bc3, bcs, bv1, bv2, bv3, bvs,
                                     WcF8, WvcatT, bcv);
  k_ec8<<<2048, 256, 0, stream>>>(edge_ctx, ecf8);
  k_w12<<<dim3(4, 32, 2), 256, 0, stream>>>(WpcT, Wpe, W1F8, W2F8);
  k_bias<<<1024, 256, 0, stream>>>(WpcT, bpe, bpc, b12);
  k_ht6<<<dim3(16, 32, 2), 512, 0, stream>>>(ecf8, W1F8, W2F8, b12, HU, TU);
  k_out9<<<dim3(256, 2), 512, 0, stream>>>(HU, TU, WcF8, WvcatT,
                                           pair_idx, vis_rep, pacc);
  k_fin<<<128, 256, 0, stream>>>(pacc, bcv, pair_pred, freq, out);
}